// Round 17
// baseline (181.572 us; speedup 1.0000x reference)
//
#include <hip/hip_runtime.h>

#define N_NODES 20000
#define N_EDGES 320000
#define IN_CH 256
#define HID_CH 512
#define NB_SCAN ((N_NODES + 255) / 256)  // 79

typedef unsigned short u16;
typedef __attribute__((ext_vector_type(4))) float f32x4;
typedef __attribute__((ext_vector_type(8))) short bf16x8;
typedef __attribute__((ext_vector_type(4))) u16 u16x4;
typedef __attribute__((ext_vector_type(8))) u16 u16x8;

__device__ __forceinline__ float bf2f(u16 h) { return __uint_as_float((unsigned)h << 16); }
__device__ __forceinline__ u16 f2bf(float f) {  // round-to-nearest-even
    unsigned u = __float_as_uint(f);
    return (u16)((u + 0x7fffu + ((u >> 16) & 1u)) >> 16);
}

// ---------------------------------------------------------------- CSR build
__global__ void zero2_kernel(int* __restrict__ a, int* __restrict__ b, int n) {
    int i = blockIdx.x * blockDim.x + threadIdx.x;
    if (i < n) { a[i] = 0; b[i] = 0; }
}

__global__ void count_deg_kernel(const int* __restrict__ dst, int* __restrict__ deg, int E) {
    int i = blockIdx.x * blockDim.x + threadIdx.x;
    if (i < E) atomicAdd(&deg[dst[i]], 1);
}

__global__ __launch_bounds__(256) void scan_pass1(const int* __restrict__ deg,
                                                  float* __restrict__ dinv,
                                                  int* __restrict__ bsum, int N) {
    __shared__ int tmp[256];
    int t = threadIdx.x;
    int i = blockIdx.x * 256 + t;
    int d = (i < N) ? deg[i] : 0;
    if (i < N) dinv[i] = rsqrtf((float)d + 1.0f);
    tmp[t] = d;
    __syncthreads();
#pragma unroll
    for (int off = 128; off > 0; off >>= 1) {
        if (t < off) tmp[t] += tmp[t + off];
        __syncthreads();
    }
    if (t == 0) bsum[blockIdx.x] = tmp[0];
}

__global__ __launch_bounds__(128) void scan_pass2(int* __restrict__ bsum, int NB) {
    __shared__ int tmp[128];
    int t = threadIdx.x;
    tmp[t] = (t < NB) ? bsum[t] : 0;
    __syncthreads();
#pragma unroll
    for (int off = 1; off < 128; off <<= 1) {
        int v = (t >= off) ? tmp[t - off] : 0;
        __syncthreads();
        tmp[t] += v;
        __syncthreads();
    }
    if (t < NB) bsum[t] = (t == 0) ? 0 : tmp[t - 1];
}

__global__ __launch_bounds__(256) void scan_pass3(const int* __restrict__ deg,
                                                  const int* __restrict__ bsum,
                                                  int* __restrict__ row_ptr, int N, int E) {
    __shared__ int tmp[256];
    int t = threadIdx.x;
    int i = blockIdx.x * 256 + t;
    int d = (i < N) ? deg[i] : 0;
    tmp[t] = d;
    __syncthreads();
#pragma unroll
    for (int off = 1; off < 256; off <<= 1) {
        int v = (t >= off) ? tmp[t - off] : 0;
        __syncthreads();
        tmp[t] += v;
        __syncthreads();
    }
    if (i < N) row_ptr[i] = bsum[blockIdx.x] + tmp[t] - d;
    if (i == 0) row_ptr[N] = E;
}

__global__ void scatter_edges_kernel(const int* __restrict__ src, const int* __restrict__ dst,
                                     const int* __restrict__ row_ptr, int* __restrict__ cursor,
                                     const float* __restrict__ dinv, int2* __restrict__ epair,
                                     int E) {
    int e = blockIdx.x * blockDim.x + threadIdx.x;
    if (e >= E) return;
    int d = dst[e];
    int s = src[e];
    int pos = row_ptr[d] + atomicAdd(&cursor[d], 1);
    epair[pos] = make_int2(s, __float_as_int(dinv[s]));
}

// ---------------------------------------------------------------- conversions
__global__ void f32_to_bf16_kernel(const float* __restrict__ in, u16* __restrict__ out, int n4) {
    int i = blockIdx.x * blockDim.x + threadIdx.x;
    if (i >= n4) return;
    float4 v = ((const float4*)in)[i];
    u16x4 o = {f2bf(v.x), f2bf(v.y), f2bf(v.z), f2bf(v.w)};
    ((u16x4*)out)[i] = o;
}

__global__ __launch_bounds__(256) void convert_w_kernel(const float* __restrict__ W1,
                                                        u16* __restrict__ hi1, u16* __restrict__ lo1,
                                                        const float* __restrict__ W2,
                                                        u16* __restrict__ hi2, u16* __restrict__ lo2) {
    __shared__ float t[64][65];
    int b = blockIdx.x;
    const float* W;
    u16 *hi, *lo;
    int K;
    if (b < 32) { W = W1; hi = hi1; lo = lo1; K = IN_CH; }
    else        { b -= 32; W = W2; hi = hi2; lo = lo2; K = HID_CH; }
    const int N = HID_CH;
    int k0 = (b >> 3) * 64, n0 = (b & 7) * 64;
    int c = threadIdx.x & 63, r4 = threadIdx.x >> 6;
#pragma unroll
    for (int i = 0; i < 16; ++i) {
        int r = i * 4 + r4;
        t[r][c] = W[(size_t)(k0 + r) * N + n0 + c];
    }
    __syncthreads();
#pragma unroll
    for (int i = 0; i < 16; ++i) {
        int n = i * 4 + r4;
        float f = t[c][n];
        u16 hb = f2bf(f);
        size_t o = (size_t)(n0 + n) * K + k0 + c;
        hi[o] = hb;
        lo[o] = f2bf(f - bf2f(hb));
    }
}

// ---------------------------------------------------------------- XCD-sliced gather, group-per-node
template <int C, int SLICES>
__global__ __launch_bounds__(256) void gather_agg_kernel(
        const u16* __restrict__ h, const int2* __restrict__ epair,
        const int* __restrict__ row_ptr, const float* __restrict__ dinv,
        u16* __restrict__ z, int N) {
    int bid = blockIdx.x;
    int nb, s;
    if (SLICES == 8) {
        nb = bid >> 3;
        s = bid & 7;
    } else {
        nb = (bid >> 3) * 2 + (bid & 1);
        s = (bid & 7) >> 1;
    }
    int t = threadIdx.x;
    int grp = t >> 3;
    int u = t & 7;
    int n = nb * 32 + grp;
    bool alive = (n < N);
    int nn = alive ? n : (N - 1);
    float dn = dinv[nn];
    const u16* hbase = h + s * 64 + u * 8;
    float acc[8];
    {
        u16x8 ws = *(const u16x8*)(hbase + (size_t)nn * C);
        float sf = dn * dn;
#pragma unroll
        for (int j = 0; j < 8; ++j) acc[j] = bf2f(ws[j]) * sf;
    }
    int e0 = row_ptr[nn];
    int e1 = alive ? row_ptr[nn + 1] : e0;
    int e = e0;
    for (; e + 4 <= e1; e += 4) {
        int2 p0 = epair[e + 0], p1 = epair[e + 1], p2 = epair[e + 2], p3 = epair[e + 3];
        u16x8 w0 = *(const u16x8*)(hbase + (size_t)p0.x * C);
        u16x8 w1 = *(const u16x8*)(hbase + (size_t)p1.x * C);
        u16x8 w2 = *(const u16x8*)(hbase + (size_t)p2.x * C);
        u16x8 w3 = *(const u16x8*)(hbase + (size_t)p3.x * C);
        float n0 = __int_as_float(p0.y) * dn, n1 = __int_as_float(p1.y) * dn;
        float n2 = __int_as_float(p2.y) * dn, n3 = __int_as_float(p3.y) * dn;
#pragma unroll
        for (int j = 0; j < 8; ++j) {
            acc[j] = fmaf(bf2f(w0[j]), n0, acc[j]);
            acc[j] = fmaf(bf2f(w1[j]), n1, acc[j]);
            acc[j] = fmaf(bf2f(w2[j]), n2, acc[j]);
            acc[j] = fmaf(bf2f(w3[j]), n3, acc[j]);
        }
    }
    for (; e < e1; ++e) {
        int2 p = epair[e];
        u16x8 w = *(const u16x8*)(hbase + (size_t)p.x * C);
        float nr = __int_as_float(p.y) * dn;
#pragma unroll
        for (int j = 0; j < 8; ++j) acc[j] = fmaf(bf2f(w[j]), nr, acc[j]);
    }
    if (alive) {
        u16x8 vh;
#pragma unroll
        for (int j = 0; j < 8; ++j) vh[j] = f2bf(acc[j]);
        *(u16x8*)(z + (size_t)n * C + s * 64 + u * 8) = vh;
    }
}

// ---------------------------------------------------------------- 2-term split-bf16 MFMA GEMM
// C = A_hi @ (B_hi + B_lo) + bias;  B transposed [N][K].  BM=128, BN=128, BK=32; 8 waves.
// 4-deep LDS pipeline (A+Bh 16KB x 4 = 64KB -> 2 blocks/CU); B_lo via register prefetch.
// R17 fix of R16's NaN: the counted vmcnt assumed a VMEM ISSUE ORDER the compiler never
// promised (B_lo reg-loads could reorder around global_load_lds; prologue had no fences)
// -> under-wait -> barrier passed with buf in flight -> garbage bf16 (NaN encodings),
// unmasked in the fp32-output layer (gemm1's relu scrubs NaN, hence h1 looked clean).
// Fix: sched_barrier(0) pins STAGE-before-BLLOAD in every block and pins the prologue;
// waits lowered by 2 (the extra waited op is an already-consumed BLLOAD -> free):
//   pinned exact newer-than-stage(t): t=0:6, t=1:8, steady:10, NT-2:8, NT-1:6
//   used:                             t=0:6, t=1:6, steady:8,  NT-2:6, NT-1:4
template <int K, bool RELU, bool OUT_BF16>
__global__ __launch_bounds__(512, 4) void gemm_mfma_kernel(
        const u16* __restrict__ A, const u16* __restrict__ Bh, const u16* __restrict__ Bl,
        const float* __restrict__ bias, void* __restrict__ Cout, int M, int N) {
    // per buffer (bytes): A@0 (8K), Bh@8192 (8K) = 16KB; 4 buffers = 64KB
    __shared__ u16 lds[4][8192];
    const int tid = threadIdx.x;
    const int lane = tid & 63;
    const int wid = tid >> 6;  // 0..7

    // bijective XCD-chunked swizzle (m204)
    const int nmt = (M + 127) / 128;
    const int total = nmt * 4;
    int bid = blockIdx.x;
    int q = total >> 3, r = total & 7;
    int xcd = bid & 7, pp = bid >> 3;
    int lin = (xcd < r) ? (xcd * (q + 1) + pp) : (r * (q + 1) + (xcd - r) * q + pp);
    const int bm = (lin >> 2) * 128;
    const int bn = (lin & 3) * 128;

    const int wm = (wid & 1) * 64;   // 2 wave-rows
    const int wn = (wid >> 1) * 32;  // 4 wave-cols

    f32x4 acc[4][2];
#pragma unroll
    for (int i = 0; i < 4; ++i)
#pragma unroll
        for (int j = 0; j < 2; ++j) acc[i][j] = (f32x4){0.f, 0.f, 0.f, 0.f};

    // staging: per plane 512 chunks of 16B, 1 chunk/thread (512 threads).
    const int srow = (wid << 4) + (lane >> 2);  // 0..127  (row = tid>>2)
    const int scb = (((lane & 3) ^ ((lane >> 3) & 3)) << 4);  // pre-swizzled source col
    const char* srcA  = (const char*)(A  + (size_t)min(bm + srow, M - 1) * K) + scb;
    const char* srcBh = (const char*)(Bh + (size_t)(bn + srow) * K) + scb;
    const int dstoff = wid << 10;  // wave-uniform (HW adds lane*16)

    // B_lo register-prefetch addressing (direct global, MFMA fragment layout)
    const int kfrag = (lane >> 4) << 3;  // k element offset within 32-k step
    const u16* Bl0p = Bl + (size_t)(bn + wn + (lane & 15)) * K + kfrag;
    const u16* Bl1p = Bl + (size_t)(bn + wn + 16 + (lane & 15)) * K + kfrag;
    bf16x8 blr[2][2];

#define GLL(srcp, dstb)                                                                  \
    __builtin_amdgcn_global_load_lds(                                                    \
        (const __attribute__((address_space(1))) void*)(srcp),                           \
        (__attribute__((address_space(3))) void*)((char*)&lds[buf][0] + (dstb)), 16, 0, 0)

#define STAGE(bufv, k0)                                                                  \
    do {                                                                                 \
        int buf = (bufv);                                                                \
        size_t kb2 = (size_t)(k0) * 2;                                                   \
        GLL(srcA + kb2, dstoff);                                                         \
        GLL(srcBh + kb2, 8192 + dstoff);                                                 \
    } while (0)

#define BLLOAD(setv, k0)                                                                 \
    do {                                                                                 \
        int set = (setv);                                                                \
        blr[set][0] = *(const bf16x8*)(Bl0p + (k0));                                     \
        blr[set][1] = *(const bf16x8*)(Bl1p + (k0));                                     \
    } while (0)

    // prologue with PINNED issue order: S0 | S1 | S2 | BL0
    STAGE(0, 0);
    __builtin_amdgcn_sched_barrier(0);
    STAGE(1, 32);
    __builtin_amdgcn_sched_barrier(0);
    STAGE(2, 64);
    __builtin_amdgcn_sched_barrier(0);
    BLLOAD(0, 0);
    __builtin_amdgcn_sched_barrier(0);

    const int NT = K / 32;
    const int kb = (lane >> 4) << 4;  // fragment k byte-offset within 64B row
#pragma unroll
    for (int t = 0; t < NT; ++t) {
        // counted waits, each <= pinned exact newer-count (see header)
        if (t == 0) {
            asm volatile("s_waitcnt vmcnt(6)" ::: "memory");
        } else if (t == NT - 1) {
            asm volatile("s_waitcnt vmcnt(4)" ::: "memory");
        } else if (t == 1 || t == NT - 2) {
            asm volatile("s_waitcnt vmcnt(6)" ::: "memory");
        } else {
            asm volatile("s_waitcnt vmcnt(8)" ::: "memory");
        }
        __builtin_amdgcn_s_barrier();   // buf[t&3] fully populated for all waves
        asm volatile("" ::: "memory");

        if (t + 3 < NT) STAGE((t + 3) & 3, (t + 3) * 32);
        __builtin_amdgcn_sched_barrier(0);  // pin: STAGE before BLLOAD
        if (t + 1 < NT) BLLOAD((t + 1) & 1, (t + 1) * 32);
        __builtin_amdgcn_sched_barrier(0);  // pin: BLLOAD before ds_reads

        const char* L = (const char*)&lds[t & 3][0];
        bf16x8 a[4], b_h[2];
#pragma unroll
        for (int i = 0; i < 4; ++i) {
            int ra = wm + i * 16 + (lane & 15);
            int off = ra * 64 + (kb ^ (((ra >> 1) & 3) << 4));
            a[i] = *(const bf16x8*)(L + off);
        }
#pragma unroll
        for (int j = 0; j < 2; ++j) {
            int rb = wn + j * 16 + (lane & 15);
            int off = rb * 64 + (kb ^ (((rb >> 1) & 3) << 4));
            b_h[j] = *(const bf16x8*)(L + 8192 + off);
        }
#pragma unroll
        for (int i = 0; i < 4; ++i)
#pragma unroll
            for (int j = 0; j < 2; ++j) {
                acc[i][j] = __builtin_amdgcn_mfma_f32_16x16x32_bf16(a[i], b_h[j], acc[i][j], 0, 0, 0);
                acc[i][j] = __builtin_amdgcn_mfma_f32_16x16x32_bf16(a[i], blr[t & 1][j], acc[i][j], 0, 0, 0);
            }
    }
#undef STAGE
#undef GLL
#undef BLLOAD

    // epilogue: C/D layout col=lane&15, row=(lane>>4)*4+t  (m89/m91 verified)
#pragma unroll
    for (int j = 0; j < 2; ++j) {
        int gc = bn + wn + j * 16 + (lane & 15);
        float bv = bias[gc];
#pragma unroll
        for (int i = 0; i < 4; ++i) {
#pragma unroll
            for (int t = 0; t < 4; ++t) {
                int gr = bm + wm + i * 16 + ((lane >> 4) << 2) + t;
                if (gr < M) {
                    float v = acc[i][j][t] + bv;
                    if (RELU) v = fmaxf(v, 0.f);
                    if (OUT_BF16)
                        ((u16*)Cout)[(size_t)gr * N + gc] = f2bf(v);
                    else
                        ((float*)Cout)[(size_t)gr * N + gc] = v;
                }
            }
        }
    }
}

// ---------------------------------------------------------------- launch
extern "C" void kernel_launch(void* const* d_in, const int* in_sizes, int n_in,
                              void* d_out, int out_size, void* d_ws, size_t ws_size,
                              hipStream_t stream) {
    const float* x  = (const float*)d_in[0];
    const int*   ei = (const int*)d_in[1];
    const float* W1 = (const float*)d_in[2];
    const float* b1 = (const float*)d_in[3];
    const float* W2 = (const float*)d_in[4];
    const float* b2 = (const float*)d_in[5];
    const int* src = ei;
    const int* dst = ei + N_EDGES;

    char* ws = (char*)d_ws;
    size_t off = 0;
    auto alloc = [&](size_t bytes) {
        void* p = ws + off;
        off = (off + bytes + 255) & ~(size_t)255;
        return p;
    };
    int*   deg     = (int*)alloc(N_NODES * 4);
    int*   cursor  = (int*)alloc(N_NODES * 4);
    int*   row_ptr = (int*)alloc((N_NODES + 1) * 4);
    float* dinv    = (float*)alloc(N_NODES * 4);
    int*   bsum    = (int*)alloc(NB_SCAN * 4);
    int2*  epair   = (int2*)alloc((size_t)N_EDGES * 8);
    u16*   wt1_hi  = (u16*)alloc((size_t)IN_CH * HID_CH * 2);
    u16*   wt1_lo  = (u16*)alloc((size_t)IN_CH * HID_CH * 2);
    u16*   wt2_hi  = (u16*)alloc((size_t)HID_CH * HID_CH * 2);
    u16*   wt2_lo  = (u16*)alloc((size_t)HID_CH * HID_CH * 2);
    u16*   xb      = (u16*)alloc((size_t)N_NODES * IN_CH * 2);   // [N, 256] bf16
    u16*   z1      = (u16*)alloc((size_t)N_NODES * IN_CH * 2);   // [N, 256] bf16 (hi only)
    u16*   z2      = (u16*)alloc((size_t)N_NODES * HID_CH * 2);  // [N, 512] bf16 (hi only)
    u16*   h1      = (u16*)d_out;  // bf16 h1 scratch in d_out (dead before final GEMM writes)

    // CSR + dinv + epair
    zero2_kernel<<<NB_SCAN, 256, 0, stream>>>(deg, cursor, N_NODES);
    count_deg_kernel<<<(N_EDGES + 255) / 256, 256, 0, stream>>>(dst, deg, N_EDGES);
    scan_pass1<<<NB_SCAN, 256, 0, stream>>>(deg, dinv, bsum, N_NODES);
    scan_pass2<<<1, 128, 0, stream>>>(bsum, NB_SCAN);
    scan_pass3<<<NB_SCAN, 256, 0, stream>>>(deg, bsum, row_ptr, N_NODES, N_EDGES);
    scatter_edges_kernel<<<(N_EDGES + 255) / 256, 256, 0, stream>>>(src, dst, row_ptr, cursor,
                                                                    dinv, epair, N_EDGES);

    // conversions
    f32_to_bf16_kernel<<<(N_NODES * IN_CH / 4 + 255) / 256, 256, 0, stream>>>(
        x, xb, N_NODES * IN_CH / 4);
    convert_w_kernel<<<96, 256, 0, stream>>>(W1, wt1_hi, wt1_lo, W2, wt2_hi, wt2_lo);

    const int NMT = (N_NODES + 127) / 128;  // 157 -> grid 628
    const int NB32 = (N_NODES + 31) / 32;   // 625 node-blocks of 32
    // layer 1: z1 = P @ xb (4 slices on XCD pairs) ; h1 = relu(z1 @ (W1h+W1l) + b1) (bf16 out)
    gather_agg_kernel<IN_CH, 4><<<((NB32 + 1) / 2) * 8, 256, 0, stream>>>(
        xb, epair, row_ptr, dinv, z1, N_NODES);
    gemm_mfma_kernel<IN_CH, true, true><<<NMT * 4, 512, 0, stream>>>(
        z1, wt1_hi, wt1_lo, b1, h1, N_NODES, HID_CH);

    // layer 2: z2 = P @ h1 (8 slices, one per XCD) ; out = z2 @ (W2h+W2l) + b2 (fp32 out)
    gather_agg_kernel<HID_CH, 8><<<NB32 * 8, 256, 0, stream>>>(
        h1, epair, row_ptr, dinv, z2, N_NODES);
    gemm_mfma_kernel<HID_CH, false, false><<<NMT * 4, 512, 0, stream>>>(
        z2, wt2_hi, wt2_lo, b2, (float*)d_out, N_NODES, HID_CH);
}

// Round 18
// 158.312 us; speedup vs baseline: 1.1469x; 1.1469x over previous
//
#include <hip/hip_runtime.h>

#define N_NODES 20000
#define N_EDGES 320000
#define IN_CH 256
#define HID_CH 512
#define NB_SCAN ((N_NODES + 255) / 256)  // 79

typedef unsigned short u16;
typedef __attribute__((ext_vector_type(4))) float f32x4;
typedef __attribute__((ext_vector_type(8))) short bf16x8;
typedef __attribute__((ext_vector_type(4))) u16 u16x4;
typedef __attribute__((ext_vector_type(8))) u16 u16x8;

__device__ __forceinline__ float bf2f(u16 h) { return __uint_as_float((unsigned)h << 16); }
__device__ __forceinline__ u16 f2bf(float f) {  // round-to-nearest-even
    unsigned u = __float_as_uint(f);
    return (u16)((u + 0x7fffu + ((u >> 16) & 1u)) >> 16);
}

// ---------------------------------------------------------------- CSR build
__global__ void zero2_kernel(int* __restrict__ a, int* __restrict__ b, int n) {
    int i = blockIdx.x * blockDim.x + threadIdx.x;
    if (i < n) { a[i] = 0; b[i] = 0; }
}

__global__ void count_deg_kernel(const int* __restrict__ dst, int* __restrict__ deg, int E) {
    int i = blockIdx.x * blockDim.x + threadIdx.x;
    if (i < E) atomicAdd(&deg[dst[i]], 1);
}

__global__ __launch_bounds__(256) void scan_pass1(const int* __restrict__ deg,
                                                  float* __restrict__ dinv,
                                                  int* __restrict__ bsum, int N) {
    __shared__ int tmp[256];
    int t = threadIdx.x;
    int i = blockIdx.x * 256 + t;
    int d = (i < N) ? deg[i] : 0;
    if (i < N) dinv[i] = rsqrtf((float)d + 1.0f);
    tmp[t] = d;
    __syncthreads();
#pragma unroll
    for (int off = 128; off > 0; off >>= 1) {
        if (t < off) tmp[t] += tmp[t + off];
        __syncthreads();
    }
    if (t == 0) bsum[blockIdx.x] = tmp[0];
}

__global__ __launch_bounds__(128) void scan_pass2(int* __restrict__ bsum, int NB) {
    __shared__ int tmp[128];
    int t = threadIdx.x;
    tmp[t] = (t < NB) ? bsum[t] : 0;
    __syncthreads();
#pragma unroll
    for (int off = 1; off < 128; off <<= 1) {
        int v = (t >= off) ? tmp[t - off] : 0;
        __syncthreads();
        tmp[t] += v;
        __syncthreads();
    }
    if (t < NB) bsum[t] = (t == 0) ? 0 : tmp[t - 1];
}

__global__ __launch_bounds__(256) void scan_pass3(const int* __restrict__ deg,
                                                  const int* __restrict__ bsum,
                                                  int* __restrict__ row_ptr, int N, int E) {
    __shared__ int tmp[256];
    int t = threadIdx.x;
    int i = blockIdx.x * 256 + t;
    int d = (i < N) ? deg[i] : 0;
    tmp[t] = d;
    __syncthreads();
#pragma unroll
    for (int off = 1; off < 256; off <<= 1) {
        int v = (t >= off) ? tmp[t - off] : 0;
        __syncthreads();
        tmp[t] += v;
        __syncthreads();
    }
    if (i < N) row_ptr[i] = bsum[blockIdx.x] + tmp[t] - d;
    if (i == 0) row_ptr[N] = E;
}

__global__ void scatter_edges_kernel(const int* __restrict__ src, const int* __restrict__ dst,
                                     const int* __restrict__ row_ptr, int* __restrict__ cursor,
                                     const float* __restrict__ dinv, int2* __restrict__ epair,
                                     int E) {
    int e = blockIdx.x * blockDim.x + threadIdx.x;
    if (e >= E) return;
    int d = dst[e];
    int s = src[e];
    int pos = row_ptr[d] + atomicAdd(&cursor[d], 1);
    epair[pos] = make_int2(s, __float_as_int(dinv[s]));
}

// ---------------------------------------------------------------- conversions
__global__ void f32_to_bf16_kernel(const float* __restrict__ in, u16* __restrict__ out, int n4) {
    int i = blockIdx.x * blockDim.x + threadIdx.x;
    if (i >= n4) return;
    float4 v = ((const float4*)in)[i];
    u16x4 o = {f2bf(v.x), f2bf(v.y), f2bf(v.z), f2bf(v.w)};
    ((u16x4*)out)[i] = o;
}

__global__ __launch_bounds__(256) void convert_w_kernel(const float* __restrict__ W1,
                                                        u16* __restrict__ hi1, u16* __restrict__ lo1,
                                                        const float* __restrict__ W2,
                                                        u16* __restrict__ hi2, u16* __restrict__ lo2) {
    __shared__ float t[64][65];
    int b = blockIdx.x;
    const float* W;
    u16 *hi, *lo;
    int K;
    if (b < 32) { W = W1; hi = hi1; lo = lo1; K = IN_CH; }
    else        { b -= 32; W = W2; hi = hi2; lo = lo2; K = HID_CH; }
    const int N = HID_CH;
    int k0 = (b >> 3) * 64, n0 = (b & 7) * 64;
    int c = threadIdx.x & 63, r4 = threadIdx.x >> 6;
#pragma unroll
    for (int i = 0; i < 16; ++i) {
        int r = i * 4 + r4;
        t[r][c] = W[(size_t)(k0 + r) * N + n0 + c];
    }
    __syncthreads();
#pragma unroll
    for (int i = 0; i < 16; ++i) {
        int n = i * 4 + r4;
        float f = t[c][n];
        u16 hb = f2bf(f);
        size_t o = (size_t)(n0 + n) * K + k0 + c;
        hi[o] = hb;
        lo[o] = f2bf(f - bf2f(hb));
    }
}

// ---------------------------------------------------------------- XCD-sliced gather, group-per-node
template <int C, int SLICES>
__global__ __launch_bounds__(256) void gather_agg_kernel(
        const u16* __restrict__ h, const int2* __restrict__ epair,
        const int* __restrict__ row_ptr, const float* __restrict__ dinv,
        u16* __restrict__ z, int N) {
    int bid = blockIdx.x;
    int nb, s;
    if (SLICES == 8) {
        nb = bid >> 3;
        s = bid & 7;
    } else {
        nb = (bid >> 3) * 2 + (bid & 1);
        s = (bid & 7) >> 1;
    }
    int t = threadIdx.x;
    int grp = t >> 3;
    int u = t & 7;
    int n = nb * 32 + grp;
    bool alive = (n < N);
    int nn = alive ? n : (N - 1);
    float dn = dinv[nn];
    const u16* hbase = h + s * 64 + u * 8;
    float acc[8];
    {
        u16x8 ws = *(const u16x8*)(hbase + (size_t)nn * C);
        float sf = dn * dn;
#pragma unroll
        for (int j = 0; j < 8; ++j) acc[j] = bf2f(ws[j]) * sf;
    }
    int e0 = row_ptr[nn];
    int e1 = alive ? row_ptr[nn + 1] : e0;
    int e = e0;
    for (; e + 4 <= e1; e += 4) {
        int2 p0 = epair[e + 0], p1 = epair[e + 1], p2 = epair[e + 2], p3 = epair[e + 3];
        u16x8 w0 = *(const u16x8*)(hbase + (size_t)p0.x * C);
        u16x8 w1 = *(const u16x8*)(hbase + (size_t)p1.x * C);
        u16x8 w2 = *(const u16x8*)(hbase + (size_t)p2.x * C);
        u16x8 w3 = *(const u16x8*)(hbase + (size_t)p3.x * C);
        float n0 = __int_as_float(p0.y) * dn, n1 = __int_as_float(p1.y) * dn;
        float n2 = __int_as_float(p2.y) * dn, n3 = __int_as_float(p3.y) * dn;
#pragma unroll
        for (int j = 0; j < 8; ++j) {
            acc[j] = fmaf(bf2f(w0[j]), n0, acc[j]);
            acc[j] = fmaf(bf2f(w1[j]), n1, acc[j]);
            acc[j] = fmaf(bf2f(w2[j]), n2, acc[j]);
            acc[j] = fmaf(bf2f(w3[j]), n3, acc[j]);
        }
    }
    for (; e < e1; ++e) {
        int2 p = epair[e];
        u16x8 w = *(const u16x8*)(hbase + (size_t)p.x * C);
        float nr = __int_as_float(p.y) * dn;
#pragma unroll
        for (int j = 0; j < 8; ++j) acc[j] = fmaf(bf2f(w[j]), nr, acc[j]);
    }
    if (alive) {
        u16x8 vh;
#pragma unroll
        for (int j = 0; j < 8; ++j) vh[j] = f2bf(acc[j]);
        *(u16x8*)(z + (size_t)n * C + s * 64 + u * 8) = vh;
    }
}

// ---------------------------------------------------------------- 2-term split-bf16 MFMA GEMM
// C = A_hi @ (B_hi + B_lo) + bias;  B transposed [N][K].  BM=128, BN=128, BK=32; 8 waves
// (2x4 of 64x32). R18: DOUBLE-buffered all-LDS (2 x 24KB = 48KB) -> 3 blocks/CU
// (144/160 KB LDS), 24 waves/CU = +50% TLP over R15's 2 blocks. Cross-round scaling law
// (R7:16w=54us 3-term, R9:12w=66us, R15:16w=44us 2-term): latency-bound GEMM time
// ~ 1/resident-waves; source-level deeper pipelining is null (R15) or negative (R16/R17,
// reverted). Structure = R7's proven 2-barrier counted-vmcnt loop with 3 loads/stage:
// STAGE(next); vmcnt(3)=prev-tile loads done, own 3 in flight; barrier; compute; barrier.
// LDS swizzle slot ^= (row>>1)&3 (R7-measured: 0 conflicts).
template <int K, bool RELU, bool OUT_BF16>
__global__ __launch_bounds__(512, 6) void gemm_mfma_kernel(
        const u16* __restrict__ A, const u16* __restrict__ Bh, const u16* __restrict__ Bl,
        const float* __restrict__ bias, void* __restrict__ Cout, int M, int N) {
    // per buffer (bytes): A@0 (8K), Bh@8192 (8K), Bl@16384 (8K) = 24KB; x2 = 48KB
    __shared__ u16 lds[2][12288];
    const int tid = threadIdx.x;
    const int lane = tid & 63;
    const int wid = tid >> 6;  // 0..7

    // bijective XCD-chunked swizzle (m204)
    const int nmt = (M + 127) / 128;
    const int total = nmt * 4;
    int bid = blockIdx.x;
    int q = total >> 3, r = total & 7;
    int xcd = bid & 7, pp = bid >> 3;
    int lin = (xcd < r) ? (xcd * (q + 1) + pp) : (r * (q + 1) + (xcd - r) * q + pp);
    const int bm = (lin >> 2) * 128;
    const int bn = (lin & 3) * 128;

    const int wm = (wid & 1) * 64;   // 2 wave-rows
    const int wn = (wid >> 1) * 32;  // 4 wave-cols

    f32x4 acc[4][2];
#pragma unroll
    for (int i = 0; i < 4; ++i)
#pragma unroll
        for (int j = 0; j < 2; ++j) acc[i][j] = (f32x4){0.f, 0.f, 0.f, 0.f};

    // staging: per plane 512 chunks of 16B, 1 chunk/thread (512 threads).
    const int srow = (wid << 4) + (lane >> 2);  // 0..127  (row = tid>>2)
    const int scb = (((lane & 3) ^ ((lane >> 3) & 3)) << 4);  // pre-swizzled source col
    const char* srcA  = (const char*)(A  + (size_t)min(bm + srow, M - 1) * K) + scb;
    const char* srcBh = (const char*)(Bh + (size_t)(bn + srow) * K) + scb;
    const char* srcBl = (const char*)(Bl + (size_t)(bn + srow) * K) + scb;
    const int dstoff = wid << 10;  // wave-uniform (HW adds lane*16)

#define GLL(srcp, dstb)                                                                  \
    __builtin_amdgcn_global_load_lds(                                                    \
        (const __attribute__((address_space(1))) void*)(srcp),                           \
        (__attribute__((address_space(3))) void*)((char*)&lds[buf][0] + (dstb)), 16, 0, 0)

#define STAGE(bufv, k0)                                                                  \
    do {                                                                                 \
        int buf = (bufv);                                                                \
        size_t kb2 = (size_t)(k0) * 2;                                                   \
        GLL(srcA + kb2, dstoff);                                                         \
        GLL(srcBh + kb2, 8192 + dstoff);                                                 \
        GLL(srcBl + kb2, 16384 + dstoff);                                                \
    } while (0)

    STAGE(0, 0);

    const int NT = K / 32;
    const int kb = (lane >> 4) << 4;  // fragment k byte-offset within 64B row
#pragma unroll
    for (int t = 0; t < NT; ++t) {
        int cur = t & 1;
        if (t + 1 < NT) {
            STAGE(cur ^ 1, (t + 1) * 32);
            asm volatile("s_waitcnt vmcnt(3)" ::: "memory");  // prev-tile loads done
        } else {
            asm volatile("s_waitcnt vmcnt(0)" ::: "memory");
        }
        __builtin_amdgcn_s_barrier();   // all waves: buf[cur] fully populated
        asm volatile("" ::: "memory");

        const char* L = (const char*)&lds[cur][0];
        bf16x8 a[4], b_h[2], b_l[2];
#pragma unroll
        for (int i = 0; i < 4; ++i) {
            int ra = wm + i * 16 + (lane & 15);
            int off = ra * 64 + (kb ^ (((ra >> 1) & 3) << 4));
            a[i] = *(const bf16x8*)(L + off);
        }
#pragma unroll
        for (int j = 0; j < 2; ++j) {
            int rb = wn + j * 16 + (lane & 15);
            int off = rb * 64 + (kb ^ (((rb >> 1) & 3) << 4));
            b_h[j] = *(const bf16x8*)(L + 8192 + off);
            b_l[j] = *(const bf16x8*)(L + 16384 + off);
        }
#pragma unroll
        for (int i = 0; i < 4; ++i)
#pragma unroll
            for (int j = 0; j < 2; ++j) {
                acc[i][j] = __builtin_amdgcn_mfma_f32_16x16x32_bf16(a[i], b_h[j], acc[i][j], 0, 0, 0);
                acc[i][j] = __builtin_amdgcn_mfma_f32_16x16x32_bf16(a[i], b_l[j], acc[i][j], 0, 0, 0);
            }
        asm volatile("" ::: "memory");
        __builtin_amdgcn_s_barrier();   // all waves done reading buf[cur]
    }
#undef STAGE
#undef GLL

    // epilogue: C/D layout col=lane&15, row=(lane>>4)*4+t  (m89/m91 verified)
#pragma unroll
    for (int j = 0; j < 2; ++j) {
        int gc = bn + wn + j * 16 + (lane & 15);
        float bv = bias[gc];
#pragma unroll
        for (int i = 0; i < 4; ++i) {
#pragma unroll
            for (int t = 0; t < 4; ++t) {
                int gr = bm + wm + i * 16 + ((lane >> 4) << 2) + t;
                if (gr < M) {
                    float v = acc[i][j][t] + bv;
                    if (RELU) v = fmaxf(v, 0.f);
                    if (OUT_BF16)
                        ((u16*)Cout)[(size_t)gr * N + gc] = f2bf(v);
                    else
                        ((float*)Cout)[(size_t)gr * N + gc] = v;
                }
            }
        }
    }
}

// ---------------------------------------------------------------- launch
extern "C" void kernel_launch(void* const* d_in, const int* in_sizes, int n_in,
                              void* d_out, int out_size, void* d_ws, size_t ws_size,
                              hipStream_t stream) {
    const float* x  = (const float*)d_in[0];
    const int*   ei = (const int*)d_in[1];
    const float* W1 = (const float*)d_in[2];
    const float* b1 = (const float*)d_in[3];
    const float* W2 = (const float*)d_in[4];
    const float* b2 = (const float*)d_in[5];
    const int* src = ei;
    const int* dst = ei + N_EDGES;

    char* ws = (char*)d_ws;
    size_t off = 0;
    auto alloc = [&](size_t bytes) {
        void* p = ws + off;
        off = (off + bytes + 255) & ~(size_t)255;
        return p;
    };
    int*   deg     = (int*)alloc(N_NODES * 4);
    int*   cursor  = (int*)alloc(N_NODES * 4);
    int*   row_ptr = (int*)alloc((N_NODES + 1) * 4);
    float* dinv    = (float*)alloc(N_NODES * 4);
    int*   bsum    = (int*)alloc(NB_SCAN * 4);
    int2*  epair   = (int2*)alloc((size_t)N_EDGES * 8);
    u16*   wt1_hi  = (u16*)alloc((size_t)IN_CH * HID_CH * 2);
    u16*   wt1_lo  = (u16*)alloc((size_t)IN_CH * HID_CH * 2);
    u16*   wt2_hi  = (u16*)alloc((size_t)HID_CH * HID_CH * 2);
    u16*   wt2_lo  = (u16*)alloc((size_t)HID_CH * HID_CH * 2);
    u16*   xb      = (u16*)alloc((size_t)N_NODES * IN_CH * 2);   // [N, 256] bf16
    u16*   z1      = (u16*)alloc((size_t)N_NODES * IN_CH * 2);   // [N, 256] bf16 (hi only)
    u16*   z2      = (u16*)alloc((size_t)N_NODES * HID_CH * 2);  // [N, 512] bf16 (hi only)
    u16*   h1      = (u16*)d_out;  // bf16 h1 scratch in d_out (dead before final GEMM writes)

    // CSR + dinv + epair
    zero2_kernel<<<NB_SCAN, 256, 0, stream>>>(deg, cursor, N_NODES);
    count_deg_kernel<<<(N_EDGES + 255) / 256, 256, 0, stream>>>(dst, deg, N_EDGES);
    scan_pass1<<<NB_SCAN, 256, 0, stream>>>(deg, dinv, bsum, N_NODES);
    scan_pass2<<<1, 128, 0, stream>>>(bsum, NB_SCAN);
    scan_pass3<<<NB_SCAN, 256, 0, stream>>>(deg, bsum, row_ptr, N_NODES, N_EDGES);
    scatter_edges_kernel<<<(N_EDGES + 255) / 256, 256, 0, stream>>>(src, dst, row_ptr, cursor,
                                                                    dinv, epair, N_EDGES);

    // conversions
    f32_to_bf16_kernel<<<(N_NODES * IN_CH / 4 + 255) / 256, 256, 0, stream>>>(
        x, xb, N_NODES * IN_CH / 4);
    convert_w_kernel<<<96, 256, 0, stream>>>(W1, wt1_hi, wt1_lo, W2, wt2_hi, wt2_lo);

    const int NMT = (N_NODES + 127) / 128;  // 157 -> grid 628
    const int NB32 = (N_NODES + 31) / 32;   // 625 node-blocks of 32
    // layer 1: z1 = P @ xb (4 slices on XCD pairs) ; h1 = relu(z1 @ (W1h+W1l) + b1) (bf16 out)
    gather_agg_kernel<IN_CH, 4><<<((NB32 + 1) / 2) * 8, 256, 0, stream>>>(
        xb, epair, row_ptr, dinv, z1, N_NODES);
    gemm_mfma_kernel<IN_CH, true, true><<<NMT * 4, 512, 0, stream>>>(
        z1, wt1_hi, wt1_lo, b1, h1, N_NODES, HID_CH);

    // layer 2: z2 = P @ h1 (8 slices, one per XCD) ; out = z2 @ (W2h+W2l) + b2 (fp32 out)
    gather_agg_kernel<HID_CH, 8><<<NB32 * 8, 256, 0, stream>>>(
        h1, epair, row_ptr, dinv, z2, N_NODES);
    gemm_mfma_kernel<HID_CH, false, false><<<NMT * 4, 512, 0, stream>>>(
        z2, wt2_hi, wt2_lo, b2, (float*)d_out, N_NODES, HID_CH);
}

// Round 19
// 146.577 us; speedup vs baseline: 1.2387x; 1.0801x over previous
//
#include <hip/hip_runtime.h>

#define N_NODES 20000
#define N_EDGES 320000
#define IN_CH 256
#define HID_CH 512
#define NB_SCAN ((N_NODES + 255) / 256)  // 79

typedef unsigned short u16;
typedef __attribute__((ext_vector_type(4))) float f32x4;
typedef __attribute__((ext_vector_type(8))) short bf16x8;
typedef __attribute__((ext_vector_type(4))) u16 u16x4;
typedef __attribute__((ext_vector_type(8))) u16 u16x8;

__device__ __forceinline__ float bf2f(u16 h) { return __uint_as_float((unsigned)h << 16); }
__device__ __forceinline__ u16 f2bf(float f) {  // round-to-nearest-even
    unsigned u = __float_as_uint(f);
    return (u16)((u + 0x7fffu + ((u >> 16) & 1u)) >> 16);
}

// ---------------------------------------------------------------- fused prep:
// blocks [0,79): zero deg+cursor; [79, 79+5000): x f32->bf16; [5079, 5175): W transpose+split
__global__ __launch_bounds__(256) void prep_kernel(
        int* __restrict__ deg, int* __restrict__ cursor,
        const float* __restrict__ x, u16* __restrict__ xb,
        const float* __restrict__ W1, u16* __restrict__ hi1, u16* __restrict__ lo1,
        const float* __restrict__ W2, u16* __restrict__ hi2, u16* __restrict__ lo2) {
    __shared__ float t[64][65];
    int b = blockIdx.x;
    if (b < NB_SCAN) {
        int i = b * 256 + threadIdx.x;
        if (i < N_NODES) { deg[i] = 0; cursor[i] = 0; }
        return;
    }
    b -= NB_SCAN;
    const int XB = N_NODES * IN_CH / 4 / 256;  // 5000 (exact)
    if (b < XB) {
        int i = b * 256 + threadIdx.x;  // u16x4 index
        float4 v = ((const float4*)x)[i];
        u16x4 o = {f2bf(v.x), f2bf(v.y), f2bf(v.z), f2bf(v.w)};
        ((u16x4*)xb)[i] = o;
        return;
    }
    b -= XB;
    const float* W;
    u16 *hi, *lo;
    int K;
    if (b < 32) { W = W1; hi = hi1; lo = lo1; K = IN_CH; }
    else        { b -= 32; W = W2; hi = hi2; lo = lo2; K = HID_CH; }
    const int N = HID_CH;
    int k0 = (b >> 3) * 64, n0 = (b & 7) * 64;
    int c = threadIdx.x & 63, r4 = threadIdx.x >> 6;
#pragma unroll
    for (int i = 0; i < 16; ++i) {
        int r = i * 4 + r4;
        t[r][c] = W[(size_t)(k0 + r) * N + n0 + c];
    }
    __syncthreads();
#pragma unroll
    for (int i = 0; i < 16; ++i) {
        int n = i * 4 + r4;
        float f = t[c][n];
        u16 hb = f2bf(f);
        size_t o = (size_t)(n0 + n) * K + k0 + c;
        hi[o] = hb;
        lo[o] = f2bf(f - bf2f(hb));
    }
}

// ---------------------------------------------------------------- CSR build
__global__ void count_deg_kernel(const int* __restrict__ dst, int* __restrict__ deg, int E) {
    int i = blockIdx.x * blockDim.x + threadIdx.x;
    if (i < E) atomicAdd(&deg[dst[i]], 1);
}

__global__ __launch_bounds__(256) void scan_pass1(const int* __restrict__ deg,
                                                  float* __restrict__ dinv,
                                                  int* __restrict__ bsum, int N) {
    __shared__ int tmp[256];
    int t = threadIdx.x;
    int i = blockIdx.x * 256 + t;
    int d = (i < N) ? deg[i] : 0;
    if (i < N) dinv[i] = rsqrtf((float)d + 1.0f);
    tmp[t] = d;
    __syncthreads();
#pragma unroll
    for (int off = 128; off > 0; off >>= 1) {
        if (t < off) tmp[t] += tmp[t + off];
        __syncthreads();
    }
    if (t == 0) bsum[blockIdx.x] = tmp[0];
}

// pass3 with pass2 FUSED: each block re-scans the 79 bsums locally (cheaper than a
// dedicated 1-block launch), then block-local exclusive scan of deg -> row_ptr
__global__ __launch_bounds__(256) void scan_pass3(const int* __restrict__ deg,
                                                  const int* __restrict__ bsum,
                                                  int* __restrict__ row_ptr, int N, int E) {
    __shared__ int tmp[256];
    __shared__ int bs[128];
    int t = threadIdx.x;
    if (t < 128) bs[t] = (t < NB_SCAN) ? bsum[t] : 0;
    __syncthreads();
#pragma unroll
    for (int off = 1; off < 128; off <<= 1) {
        int v = (t >= off && t < 128) ? bs[t - off] : 0;
        __syncthreads();
        if (t < 128) bs[t] += v;
        __syncthreads();
    }
    int base = (blockIdx.x == 0) ? 0 : bs[blockIdx.x - 1];
    int i = blockIdx.x * 256 + t;
    int d = (i < N) ? deg[i] : 0;
    tmp[t] = d;
    __syncthreads();
#pragma unroll
    for (int off = 1; off < 256; off <<= 1) {
        int v = (t >= off) ? tmp[t - off] : 0;
        __syncthreads();
        tmp[t] += v;
        __syncthreads();
    }
    if (i < N) row_ptr[i] = base + tmp[t] - d;
    if (i == 0) row_ptr[N] = E;
}

__global__ void scatter_edges_kernel(const int* __restrict__ src, const int* __restrict__ dst,
                                     const int* __restrict__ row_ptr, int* __restrict__ cursor,
                                     const float* __restrict__ dinv, int2* __restrict__ epair,
                                     int E) {
    int e = blockIdx.x * blockDim.x + threadIdx.x;
    if (e >= E) return;
    int d = dst[e];
    int s = src[e];
    int pos = row_ptr[d] + atomicAdd(&cursor[d], 1);
    epair[pos] = make_int2(s, __float_as_int(dinv[s]));
}

// ---------------------------------------------------------------- XCD-sliced gather, group-per-node
template <int C, int SLICES>
__global__ __launch_bounds__(256) void gather_agg_kernel(
        const u16* __restrict__ h, const int2* __restrict__ epair,
        const int* __restrict__ row_ptr, const float* __restrict__ dinv,
        u16* __restrict__ z, int N) {
    int bid = blockIdx.x;
    int nb, s;
    if (SLICES == 8) {
        nb = bid >> 3;
        s = bid & 7;
    } else {
        nb = (bid >> 3) * 2 + (bid & 1);
        s = (bid & 7) >> 1;
    }
    int t = threadIdx.x;
    int grp = t >> 3;
    int u = t & 7;
    int n = nb * 32 + grp;
    bool alive = (n < N);
    int nn = alive ? n : (N - 1);
    float dn = dinv[nn];
    const u16* hbase = h + s * 64 + u * 8;
    float acc[8];
    {
        u16x8 ws = *(const u16x8*)(hbase + (size_t)nn * C);
        float sf = dn * dn;
#pragma unroll
        for (int j = 0; j < 8; ++j) acc[j] = bf2f(ws[j]) * sf;
    }
    int e0 = row_ptr[nn];
    int e1 = alive ? row_ptr[nn + 1] : e0;
    int e = e0;
    for (; e + 4 <= e1; e += 4) {
        int2 p0 = epair[e + 0], p1 = epair[e + 1], p2 = epair[e + 2], p3 = epair[e + 3];
        u16x8 w0 = *(const u16x8*)(hbase + (size_t)p0.x * C);
        u16x8 w1 = *(const u16x8*)(hbase + (size_t)p1.x * C);
        u16x8 w2 = *(const u16x8*)(hbase + (size_t)p2.x * C);
        u16x8 w3 = *(const u16x8*)(hbase + (size_t)p3.x * C);
        float n0 = __int_as_float(p0.y) * dn, n1 = __int_as_float(p1.y) * dn;
        float n2 = __int_as_float(p2.y) * dn, n3 = __int_as_float(p3.y) * dn;
#pragma unroll
        for (int j = 0; j < 8; ++j) {
            acc[j] = fmaf(bf2f(w0[j]), n0, acc[j]);
            acc[j] = fmaf(bf2f(w1[j]), n1, acc[j]);
            acc[j] = fmaf(bf2f(w2[j]), n2, acc[j]);
            acc[j] = fmaf(bf2f(w3[j]), n3, acc[j]);
        }
    }
    for (; e < e1; ++e) {
        int2 p = epair[e];
        u16x8 w = *(const u16x8*)(hbase + (size_t)p.x * C);
        float nr = __int_as_float(p.y) * dn;
#pragma unroll
        for (int j = 0; j < 8; ++j) acc[j] = fmaf(bf2f(w[j]), nr, acc[j]);
    }
    if (alive) {
        u16x8 vh;
#pragma unroll
        for (int j = 0; j < 8; ++j) vh[j] = f2bf(acc[j]);
        *(u16x8*)(z + (size_t)n * C + s * 64 + u * 8) = vh;
    }
}

// ---------------------------------------------------------------- split-bf16 MFMA GEMM
// TWO_TERM: C = A_hi @ (B_hi + B_lo) + bias (gemm2 -- fp32 output drives absmax).
// !TWO_TERM: C = A_hi @ B_hi + bias (gemm1 -- h1 is bf16 anyway; the dropped W1_lo term
//   (rms ~5.8e-4) is at h1's own bf16 rounding floor (~5.9e-4) -> accuracy-free).
//   One-term: buffer 16KB x2 = 32KB -> 4 blocks/CU = 32 waves/CU (hardware max).
// R18 structure otherwise: BM=128 BN=128 BK=32, 8 waves, dbuf, 2-barrier counted-vmcnt,
// swizzle slot ^= (row>>1)&3 (R7-measured 0 conflicts).
template <int K, bool RELU, bool OUT_BF16, bool TWO_TERM>
__global__ __launch_bounds__(512, TWO_TERM ? 6 : 8) void gemm_mfma_kernel(
        const u16* __restrict__ A, const u16* __restrict__ Bh, const u16* __restrict__ Bl,
        const float* __restrict__ bias, void* __restrict__ Cout, int M, int N) {
    // per buffer (bytes): A@0 (8K), Bh@8192 (8K)[, Bl@16384 (8K)]
    __shared__ u16 lds[2][TWO_TERM ? 12288 : 8192];
    const int tid = threadIdx.x;
    const int lane = tid & 63;
    const int wid = tid >> 6;  // 0..7

    // bijective XCD-chunked swizzle (m204)
    const int nmt = (M + 127) / 128;
    const int total = nmt * 4;
    int bid = blockIdx.x;
    int q = total >> 3, r = total & 7;
    int xcd = bid & 7, pp = bid >> 3;
    int lin = (xcd < r) ? (xcd * (q + 1) + pp) : (r * (q + 1) + (xcd - r) * q + pp);
    const int bm = (lin >> 2) * 128;
    const int bn = (lin & 3) * 128;

    const int wm = (wid & 1) * 64;   // 2 wave-rows
    const int wn = (wid >> 1) * 32;  // 4 wave-cols

    f32x4 acc[4][2];
#pragma unroll
    for (int i = 0; i < 4; ++i)
#pragma unroll
        for (int j = 0; j < 2; ++j) acc[i][j] = (f32x4){0.f, 0.f, 0.f, 0.f};

    // staging: per plane 512 chunks of 16B, 1 chunk/thread (512 threads).
    const int srow = (wid << 4) + (lane >> 2);  // 0..127  (row = tid>>2)
    const int scb = (((lane & 3) ^ ((lane >> 3) & 3)) << 4);  // pre-swizzled source col
    const char* srcA  = (const char*)(A  + (size_t)min(bm + srow, M - 1) * K) + scb;
    const char* srcBh = (const char*)(Bh + (size_t)(bn + srow) * K) + scb;
    const char* srcBl = (const char*)(Bl + (size_t)(bn + srow) * K) + scb;
    const int dstoff = wid << 10;  // wave-uniform (HW adds lane*16)

#define GLL(srcp, dstb)                                                                  \
    __builtin_amdgcn_global_load_lds(                                                    \
        (const __attribute__((address_space(1))) void*)(srcp),                           \
        (__attribute__((address_space(3))) void*)((char*)&lds[buf][0] + (dstb)), 16, 0, 0)

#define STAGE(bufv, k0)                                                                  \
    do {                                                                                 \
        int buf = (bufv);                                                                \
        size_t kb2 = (size_t)(k0) * 2;                                                   \
        GLL(srcA + kb2, dstoff);                                                         \
        GLL(srcBh + kb2, 8192 + dstoff);                                                 \
        if (TWO_TERM) GLL(srcBl + kb2, 16384 + dstoff);                                  \
    } while (0)

    STAGE(0, 0);

    const int NT = K / 32;
    const int kb = (lane >> 4) << 4;  // fragment k byte-offset within 64B row
#pragma unroll
    for (int t = 0; t < NT; ++t) {
        int cur = t & 1;
        if (t + 1 < NT) {
            STAGE(cur ^ 1, (t + 1) * 32);
            if constexpr (TWO_TERM)
                asm volatile("s_waitcnt vmcnt(3)" ::: "memory");  // prev-tile loads done
            else
                asm volatile("s_waitcnt vmcnt(2)" ::: "memory");
        } else {
            asm volatile("s_waitcnt vmcnt(0)" ::: "memory");
        }
        __builtin_amdgcn_s_barrier();   // all waves: buf[cur] fully populated
        asm volatile("" ::: "memory");

        const char* L = (const char*)&lds[cur][0];
        bf16x8 a[4], b_h[2], b_l[2];
#pragma unroll
        for (int i = 0; i < 4; ++i) {
            int ra = wm + i * 16 + (lane & 15);
            int off = ra * 64 + (kb ^ (((ra >> 1) & 3) << 4));
            a[i] = *(const bf16x8*)(L + off);
        }
#pragma unroll
        for (int j = 0; j < 2; ++j) {
            int rb = wn + j * 16 + (lane & 15);
            int off = rb * 64 + (kb ^ (((rb >> 1) & 3) << 4));
            b_h[j] = *(const bf16x8*)(L + 8192 + off);
            if (TWO_TERM) b_l[j] = *(const bf16x8*)(L + 16384 + off);
        }
#pragma unroll
        for (int i = 0; i < 4; ++i)
#pragma unroll
            for (int j = 0; j < 2; ++j) {
                acc[i][j] = __builtin_amdgcn_mfma_f32_16x16x32_bf16(a[i], b_h[j], acc[i][j], 0, 0, 0);
                if (TWO_TERM)
                    acc[i][j] = __builtin_amdgcn_mfma_f32_16x16x32_bf16(a[i], b_l[j], acc[i][j], 0, 0, 0);
            }
        asm volatile("" ::: "memory");
        __builtin_amdgcn_s_barrier();   // all waves done reading buf[cur]
    }
#undef STAGE
#undef GLL

    // epilogue: C/D layout col=lane&15, row=(lane>>4)*4+t  (m89/m91 verified)
#pragma unroll
    for (int j = 0; j < 2; ++j) {
        int gc = bn + wn + j * 16 + (lane & 15);
        float bv = bias[gc];
#pragma unroll
        for (int i = 0; i < 4; ++i) {
#pragma unroll
            for (int t = 0; t < 4; ++t) {
                int gr = bm + wm + i * 16 + ((lane >> 4) << 2) + t;
                if (gr < M) {
                    float v = acc[i][j][t] + bv;
                    if (RELU) v = fmaxf(v, 0.f);
                    if (OUT_BF16)
                        ((u16*)Cout)[(size_t)gr * N + gc] = f2bf(v);
                    else
                        ((float*)Cout)[(size_t)gr * N + gc] = v;
                }
            }
        }
    }
}

// ---------------------------------------------------------------- launch
extern "C" void kernel_launch(void* const* d_in, const int* in_sizes, int n_in,
                              void* d_out, int out_size, void* d_ws, size_t ws_size,
                              hipStream_t stream) {
    const float* x  = (const float*)d_in[0];
    const int*   ei = (const int*)d_in[1];
    const float* W1 = (const float*)d_in[2];
    const float* b1 = (const float*)d_in[3];
    const float* W2 = (const float*)d_in[4];
    const float* b2 = (const float*)d_in[5];
    const int* src = ei;
    const int* dst = ei + N_EDGES;

    char* ws = (char*)d_ws;
    size_t off = 0;
    auto alloc = [&](size_t bytes) {
        void* p = ws + off;
        off = (off + bytes + 255) & ~(size_t)255;
        return p;
    };
    int*   deg     = (int*)alloc(N_NODES * 4);
    int*   cursor  = (int*)alloc(N_NODES * 4);
    int*   row_ptr = (int*)alloc((N_NODES + 1) * 4);
    float* dinv    = (float*)alloc(N_NODES * 4);
    int*   bsum    = (int*)alloc(NB_SCAN * 4);
    int2*  epair   = (int2*)alloc((size_t)N_EDGES * 8);
    u16*   wt1_hi  = (u16*)alloc((size_t)IN_CH * HID_CH * 2);
    u16*   wt1_lo  = (u16*)alloc((size_t)IN_CH * HID_CH * 2);
    u16*   wt2_hi  = (u16*)alloc((size_t)HID_CH * HID_CH * 2);
    u16*   wt2_lo  = (u16*)alloc((size_t)HID_CH * HID_CH * 2);
    u16*   xb      = (u16*)alloc((size_t)N_NODES * IN_CH * 2);   // [N, 256] bf16
    u16*   z1      = (u16*)alloc((size_t)N_NODES * IN_CH * 2);   // [N, 256] bf16 (hi only)
    u16*   z2      = (u16*)alloc((size_t)N_NODES * HID_CH * 2);  // [N, 512] bf16 (hi only)
    u16*   h1      = (u16*)d_out;  // bf16 h1 scratch in d_out (dead before final GEMM writes)

    // fused prep: zero deg/cursor + x->bf16 + W transpose/split  (1 launch, was 3)
    const int XB = N_NODES * IN_CH / 4 / 256;  // 5000
    prep_kernel<<<NB_SCAN + XB + 96, 256, 0, stream>>>(deg, cursor, x, xb, W1, wt1_hi, wt1_lo,
                                                       W2, wt2_hi, wt2_lo);
    // CSR + dinv + epair (scan_pass2 fused into pass3)
    count_deg_kernel<<<(N_EDGES + 255) / 256, 256, 0, stream>>>(dst, deg, N_EDGES);
    scan_pass1<<<NB_SCAN, 256, 0, stream>>>(deg, dinv, bsum, N_NODES);
    scan_pass3<<<NB_SCAN, 256, 0, stream>>>(deg, bsum, row_ptr, N_NODES, N_EDGES);
    scatter_edges_kernel<<<(N_EDGES + 255) / 256, 256, 0, stream>>>(src, dst, row_ptr, cursor,
                                                                    dinv, epair, N_EDGES);

    const int NMT = (N_NODES + 127) / 128;  // 157 -> grid 628
    const int NB32 = (N_NODES + 31) / 32;   // 625 node-blocks of 32
    // layer 1: z1 = P @ xb (4 slices on XCD pairs) ; h1 = relu(z1 @ W1h + b1) (bf16 out, 1-term)
    gather_agg_kernel<IN_CH, 4><<<((NB32 + 1) / 2) * 8, 256, 0, stream>>>(
        xb, epair, row_ptr, dinv, z1, N_NODES);
    gemm_mfma_kernel<IN_CH, true, true, false><<<NMT * 4, 512, 0, stream>>>(
        z1, wt1_hi, wt1_lo, b1, h1, N_NODES, HID_CH);

    // layer 2: z2 = P @ h1 (8 slices, one per XCD) ; out = z2 @ (W2h+W2l) + b2 (fp32, 2-term)
    gather_agg_kernel<HID_CH, 8><<<NB32 * 8, 256, 0, stream>>>(
        h1, epair, row_ptr, dinv, z2, N_NODES);
    gemm_mfma_kernel<HID_CH, false, false, true><<<NMT * 4, 512, 0, stream>>>(
        z2, wt2_hi, wt2_lo, b2, (float*)d_out, N_NODES, HID_CH);
}

// Round 20
// 144.968 us; speedup vs baseline: 1.2525x; 1.0111x over previous
//
#include <hip/hip_runtime.h>

#define N_NODES 20000
#define N_EDGES 320000
#define IN_CH 256
#define HID_CH 512
#define NB_SCAN ((N_NODES + 255) / 256)  // 79

typedef unsigned short u16;
typedef __attribute__((ext_vector_type(4))) float f32x4;
typedef __attribute__((ext_vector_type(8))) short bf16x8;
typedef __attribute__((ext_vector_type(4))) u16 u16x4;
typedef __attribute__((ext_vector_type(8))) u16 u16x8;

__device__ __forceinline__ float bf2f(u16 h) { return __uint_as_float((unsigned)h << 16); }
__device__ __forceinline__ u16 f2bf(float f) {  // round-to-nearest-even
    unsigned u = __float_as_uint(f);
    return (u16)((u + 0x7fffu + ((u >> 16) & 1u)) >> 16);
}

// ---------------------------------------------------------------- fused prep:
// blocks [0,79): zero deg+cursor; [79,79+5000): x f32->bf16; [5079,5175): W transpose (hi only)
__global__ __launch_bounds__(256) void prep_kernel(
        int* __restrict__ deg, int* __restrict__ cursor,
        const float* __restrict__ x, u16* __restrict__ xb,
        const float* __restrict__ W1, u16* __restrict__ hi1,
        const float* __restrict__ W2, u16* __restrict__ hi2) {
    __shared__ float t[64][65];
    int b = blockIdx.x;
    if (b < NB_SCAN) {
        int i = b * 256 + threadIdx.x;
        if (i < N_NODES) { deg[i] = 0; cursor[i] = 0; }
        return;
    }
    b -= NB_SCAN;
    const int XB = N_NODES * IN_CH / 4 / 256;  // 5000 (exact)
    if (b < XB) {
        int i = b * 256 + threadIdx.x;  // u16x4 index
        float4 v = ((const float4*)x)[i];
        u16x4 o = {f2bf(v.x), f2bf(v.y), f2bf(v.z), f2bf(v.w)};
        ((u16x4*)xb)[i] = o;
        return;
    }
    b -= XB;
    const float* W;
    u16* hi;
    int K;
    if (b < 32) { W = W1; hi = hi1; K = IN_CH; }
    else        { b -= 32; W = W2; hi = hi2; K = HID_CH; }
    const int N = HID_CH;
    int k0 = (b >> 3) * 64, n0 = (b & 7) * 64;
    int c = threadIdx.x & 63, r4 = threadIdx.x >> 6;
#pragma unroll
    for (int i = 0; i < 16; ++i) {
        int r = i * 4 + r4;
        t[r][c] = W[(size_t)(k0 + r) * N + n0 + c];
    }
    __syncthreads();
#pragma unroll
    for (int i = 0; i < 16; ++i) {
        int n = i * 4 + r4;
        hi[(size_t)(n0 + n) * K + k0 + c] = f2bf(t[c][n]);
    }
}

// ---------------------------------------------------------------- CSR build
__global__ void count_deg_kernel(const int* __restrict__ dst, int* __restrict__ deg, int E) {
    int i = blockIdx.x * blockDim.x + threadIdx.x;
    if (i < E) atomicAdd(&deg[dst[i]], 1);
}

__global__ __launch_bounds__(256) void scan_pass1(const int* __restrict__ deg,
                                                  float* __restrict__ dinv,
                                                  int* __restrict__ bsum, int N) {
    __shared__ int tmp[256];
    int t = threadIdx.x;
    int i = blockIdx.x * 256 + t;
    int d = (i < N) ? deg[i] : 0;
    if (i < N) dinv[i] = rsqrtf((float)d + 1.0f);
    tmp[t] = d;
    __syncthreads();
#pragma unroll
    for (int off = 128; off > 0; off >>= 1) {
        if (t < off) tmp[t] += tmp[t + off];
        __syncthreads();
    }
    if (t == 0) bsum[blockIdx.x] = tmp[0];
}

// pass3 with pass2 FUSED: each block re-scans the 79 bsums locally, then block-local scan
__global__ __launch_bounds__(256) void scan_pass3(const int* __restrict__ deg,
                                                  const int* __restrict__ bsum,
                                                  int* __restrict__ row_ptr, int N, int E) {
    __shared__ int tmp[256];
    __shared__ int bs[128];
    int t = threadIdx.x;
    if (t < 128) bs[t] = (t < NB_SCAN) ? bsum[t] : 0;
    __syncthreads();
#pragma unroll
    for (int off = 1; off < 128; off <<= 1) {
        int v = (t >= off && t < 128) ? bs[t - off] : 0;
        __syncthreads();
        if (t < 128) bs[t] += v;
        __syncthreads();
    }
    int base = (blockIdx.x == 0) ? 0 : bs[blockIdx.x - 1];
    int i = blockIdx.x * 256 + t;
    int d = (i < N) ? deg[i] : 0;
    tmp[t] = d;
    __syncthreads();
#pragma unroll
    for (int off = 1; off < 256; off <<= 1) {
        int v = (t >= off) ? tmp[t - off] : 0;
        __syncthreads();
        tmp[t] += v;
        __syncthreads();
    }
    if (i < N) row_ptr[i] = base + tmp[t] - d;
    if (i == 0) row_ptr[N] = E;
}

__global__ void scatter_edges_kernel(const int* __restrict__ src, const int* __restrict__ dst,
                                     const int* __restrict__ row_ptr, int* __restrict__ cursor,
                                     const float* __restrict__ dinv, int2* __restrict__ epair,
                                     int E) {
    int e = blockIdx.x * blockDim.x + threadIdx.x;
    if (e >= E) return;
    int d = dst[e];
    int s = src[e];
    int pos = row_ptr[d] + atomicAdd(&cursor[d], 1);
    epair[pos] = make_int2(s, __float_as_int(dinv[s]));
}

// ---------------------------------------------------------------- XCD-sliced gather, group-per-node
// R20: 8-deep edge batching (was 4) -- more in-flight L2 row loads on the latency chain.
template <int C, int SLICES>
__global__ __launch_bounds__(256) void gather_agg_kernel(
        const u16* __restrict__ h, const int2* __restrict__ epair,
        const int* __restrict__ row_ptr, const float* __restrict__ dinv,
        u16* __restrict__ z, int N) {
    int bid = blockIdx.x;
    int nb, s;
    if (SLICES == 8) {
        nb = bid >> 3;
        s = bid & 7;
    } else {
        nb = (bid >> 3) * 2 + (bid & 1);
        s = (bid & 7) >> 1;
    }
    int t = threadIdx.x;
    int grp = t >> 3;
    int u = t & 7;
    int n = nb * 32 + grp;
    bool alive = (n < N);
    int nn = alive ? n : (N - 1);
    float dn = dinv[nn];
    const u16* hbase = h + s * 64 + u * 8;
    float acc[8];
    {
        u16x8 ws = *(const u16x8*)(hbase + (size_t)nn * C);
        float sf = dn * dn;
#pragma unroll
        for (int j = 0; j < 8; ++j) acc[j] = bf2f(ws[j]) * sf;
    }
    int e0 = row_ptr[nn];
    int e1 = alive ? row_ptr[nn + 1] : e0;
    int e = e0;
    for (; e + 8 <= e1; e += 8) {
        int2 p[8];
        u16x8 w[8];
#pragma unroll
        for (int b = 0; b < 8; ++b) p[b] = epair[e + b];
#pragma unroll
        for (int b = 0; b < 8; ++b) w[b] = *(const u16x8*)(hbase + (size_t)p[b].x * C);
#pragma unroll
        for (int b = 0; b < 8; ++b) {
            float nr = __int_as_float(p[b].y) * dn;
#pragma unroll
            for (int j = 0; j < 8; ++j) acc[j] = fmaf(bf2f(w[b][j]), nr, acc[j]);
        }
    }
    for (; e + 4 <= e1; e += 4) {
        int2 p0 = epair[e + 0], p1 = epair[e + 1], p2 = epair[e + 2], p3 = epair[e + 3];
        u16x8 w0 = *(const u16x8*)(hbase + (size_t)p0.x * C);
        u16x8 w1 = *(const u16x8*)(hbase + (size_t)p1.x * C);
        u16x8 w2 = *(const u16x8*)(hbase + (size_t)p2.x * C);
        u16x8 w3 = *(const u16x8*)(hbase + (size_t)p3.x * C);
        float n0 = __int_as_float(p0.y) * dn, n1 = __int_as_float(p1.y) * dn;
        float n2 = __int_as_float(p2.y) * dn, n3 = __int_as_float(p3.y) * dn;
#pragma unroll
        for (int j = 0; j < 8; ++j) {
            acc[j] = fmaf(bf2f(w0[j]), n0, acc[j]);
            acc[j] = fmaf(bf2f(w1[j]), n1, acc[j]);
            acc[j] = fmaf(bf2f(w2[j]), n2, acc[j]);
            acc[j] = fmaf(bf2f(w3[j]), n3, acc[j]);
        }
    }
    for (; e < e1; ++e) {
        int2 p = epair[e];
        u16x8 w = *(const u16x8*)(hbase + (size_t)p.x * C);
        float nr = __int_as_float(p.y) * dn;
#pragma unroll
        for (int j = 0; j < 8; ++j) acc[j] = fmaf(bf2f(w[j]), nr, acc[j]);
    }
    if (alive) {
        u16x8 vh;
#pragma unroll
        for (int j = 0; j < 8; ++j) vh[j] = f2bf(acc[j]);
        *(u16x8*)(z + (size_t)n * C + s * 64 + u * 8) = vh;
    }
}

// ---------------------------------------------------------------- 1-term bf16 MFMA GEMM
// C = A_hi @ B_hi + bias. R20: BOTH layers 1-term. gemm2's dropped W2_lo term:
// |W2_lo| rms = |W2|*2^-8/sqrt(12) ~ 5e-5 -> sigma = sqrt(512)*rms(z2)*5e-5 ~ 9e-4,
// below the A-side bf16 sigma (~1.6e-3) that measures absmax 3.9e-3 -> predict ~5-7e-3
// (threshold 11.8e-3). Buffer A+B = 16KB x2 = 32KB -> 4 blocks/CU = 32 waves/CU (max).
// Structure: 8 waves (2x4 of 64x32), dbuf, 2-barrier counted-vmcnt, swizzle
// slot ^= (row>>1)&3 (R7-measured 0 conflicts).
template <int K, bool RELU, bool OUT_BF16>
__global__ __launch_bounds__(512, 8) void gemm_mfma_kernel(
        const u16* __restrict__ A, const u16* __restrict__ Bh,
        const float* __restrict__ bias, void* __restrict__ Cout, int M, int N) {
    // per buffer (bytes): A@0 (8K), Bh@8192 (8K) = 16KB
    __shared__ u16 lds[2][8192];
    const int tid = threadIdx.x;
    const int lane = tid & 63;
    const int wid = tid >> 6;  // 0..7

    // bijective XCD-chunked swizzle (m204)
    const int nmt = (M + 127) / 128;
    const int total = nmt * 4;
    int bid = blockIdx.x;
    int q = total >> 3, r = total & 7;
    int xcd = bid & 7, pp = bid >> 3;
    int lin = (xcd < r) ? (xcd * (q + 1) + pp) : (r * (q + 1) + (xcd - r) * q + pp);
    const int bm = (lin >> 2) * 128;
    const int bn = (lin & 3) * 128;

    const int wm = (wid & 1) * 64;   // 2 wave-rows
    const int wn = (wid >> 1) * 32;  // 4 wave-cols

    f32x4 acc[4][2];
#pragma unroll
    for (int i = 0; i < 4; ++i)
#pragma unroll
        for (int j = 0; j < 2; ++j) acc[i][j] = (f32x4){0.f, 0.f, 0.f, 0.f};

    // staging: per plane 512 chunks of 16B, 1 chunk/thread (512 threads).
    const int srow = (wid << 4) + (lane >> 2);  // 0..127  (row = tid>>2)
    const int scb = (((lane & 3) ^ ((lane >> 3) & 3)) << 4);  // pre-swizzled source col
    const char* srcA  = (const char*)(A  + (size_t)min(bm + srow, M - 1) * K) + scb;
    const char* srcBh = (const char*)(Bh + (size_t)(bn + srow) * K) + scb;
    const int dstoff = wid << 10;  // wave-uniform (HW adds lane*16)

#define GLL(srcp, dstb)                                                                  \
    __builtin_amdgcn_global_load_lds(                                                    \
        (const __attribute__((address_space(1))) void*)(srcp),                           \
        (__attribute__((address_space(3))) void*)((char*)&lds[buf][0] + (dstb)), 16, 0, 0)

#define STAGE(bufv, k0)                                                                  \
    do {                                                                                 \
        int buf = (bufv);                                                                \
        size_t kb2 = (size_t)(k0) * 2;                                                   \
        GLL(srcA + kb2, dstoff);                                                         \
        GLL(srcBh + kb2, 8192 + dstoff);                                                 \
    } while (0)

    STAGE(0, 0);

    const int NT = K / 32;
    const int kb = (lane >> 4) << 4;  // fragment k byte-offset within 64B row
#pragma unroll
    for (int t = 0; t < NT; ++t) {
        int cur = t & 1;
        if (t + 1 < NT) {
            STAGE(cur ^ 1, (t + 1) * 32);
            asm volatile("s_waitcnt vmcnt(2)" ::: "memory");  // prev-tile loads done
        } else {
            asm volatile("s_waitcnt vmcnt(0)" ::: "memory");
        }
        __builtin_amdgcn_s_barrier();   // all waves: buf[cur] fully populated
        asm volatile("" ::: "memory");

        const char* L = (const char*)&lds[cur][0];
        bf16x8 a[4], b_h[2];
#pragma unroll
        for (int i = 0; i < 4; ++i) {
            int ra = wm + i * 16 + (lane & 15);
            int off = ra * 64 + (kb ^ (((ra >> 1) & 3) << 4));
            a[i] = *(const bf16x8*)(L + off);
        }
#pragma unroll
        for (int j = 0; j < 2; ++j) {
            int rb = wn + j * 16 + (lane & 15);
            int off = rb * 64 + (kb ^ (((rb >> 1) & 3) << 4));
            b_h[j] = *(const bf16x8*)(L + 8192 + off);
        }
#pragma unroll
        for (int i = 0; i < 4; ++i)
#pragma unroll
            for (int j = 0; j < 2; ++j)
                acc[i][j] = __builtin_amdgcn_mfma_f32_16x16x32_bf16(a[i], b_h[j], acc[i][j], 0, 0, 0);
        asm volatile("" ::: "memory");
        __builtin_amdgcn_s_barrier();   // all waves done reading buf[cur]
    }
#undef STAGE
#undef GLL

    // epilogue: C/D layout col=lane&15, row=(lane>>4)*4+t  (m89/m91 verified)
#pragma unroll
    for (int j = 0; j < 2; ++j) {
        int gc = bn + wn + j * 16 + (lane & 15);
        float bv = bias[gc];
#pragma unroll
        for (int i = 0; i < 4; ++i) {
#pragma unroll
            for (int t = 0; t < 4; ++t) {
                int gr = bm + wm + i * 16 + ((lane >> 4) << 2) + t;
                if (gr < M) {
                    float v = acc[i][j][t] + bv;
                    if (RELU) v = fmaxf(v, 0.f);
                    if (OUT_BF16)
                        ((u16*)Cout)[(size_t)gr * N + gc] = f2bf(v);
                    else
                        ((float*)Cout)[(size_t)gr * N + gc] = v;
                }
            }
        }
    }
}

// ---------------------------------------------------------------- launch
extern "C" void kernel_launch(void* const* d_in, const int* in_sizes, int n_in,
                              void* d_out, int out_size, void* d_ws, size_t ws_size,
                              hipStream_t stream) {
    const float* x  = (const float*)d_in[0];
    const int*   ei = (const int*)d_in[1];
    const float* W1 = (const float*)d_in[2];
    const float* b1 = (const float*)d_in[3];
    const float* W2 = (const float*)d_in[4];
    const float* b2 = (const float*)d_in[5];
    const int* src = ei;
    const int* dst = ei + N_EDGES;

    char* ws = (char*)d_ws;
    size_t off = 0;
    auto alloc = [&](size_t bytes) {
        void* p = ws + off;
        off = (off + bytes + 255) & ~(size_t)255;
        return p;
    };
    int*   deg     = (int*)alloc(N_NODES * 4);
    int*   cursor  = (int*)alloc(N_NODES * 4);
    int*   row_ptr = (int*)alloc((N_NODES + 1) * 4);
    float* dinv    = (float*)alloc(N_NODES * 4);
    int*   bsum    = (int*)alloc(NB_SCAN * 4);
    int2*  epair   = (int2*)alloc((size_t)N_EDGES * 8);
    u16*   wt1_hi  = (u16*)alloc((size_t)IN_CH * HID_CH * 2);
    u16*   wt2_hi  = (u16*)alloc((size_t)HID_CH * HID_CH * 2);
    u16*   xb      = (u16*)alloc((size_t)N_NODES * IN_CH * 2);   // [N, 256] bf16
    u16*   z1      = (u16*)alloc((size_t)N_NODES * IN_CH * 2);   // [N, 256] bf16 (hi only)
    u16*   z2      = (u16*)alloc((size_t)N_NODES * HID_CH * 2);  // [N, 512] bf16 (hi only)
    u16*   h1      = (u16*)d_out;  // bf16 h1 scratch in d_out (dead before final GEMM writes)

    // fused prep: zero deg/cursor + x->bf16 + W transpose (hi only)
    const int XB = N_NODES * IN_CH / 4 / 256;  // 5000
    prep_kernel<<<NB_SCAN + XB + 96, 256, 0, stream>>>(deg, cursor, x, xb, W1, wt1_hi, W2,
                                                       wt2_hi);
    // CSR + dinv + epair
    count_deg_kernel<<<(N_EDGES + 255) / 256, 256, 0, stream>>>(dst, deg, N_EDGES);
    scan_pass1<<<NB_SCAN, 256, 0, stream>>>(deg, dinv, bsum, N_NODES);
    scan_pass3<<<NB_SCAN, 256, 0, stream>>>(deg, bsum, row_ptr, N_NODES, N_EDGES);
    scatter_edges_kernel<<<(N_EDGES + 255) / 256, 256, 0, stream>>>(src, dst, row_ptr, cursor,
                                                                    dinv, epair, N_EDGES);

    const int NMT = (N_NODES + 127) / 128;  // 157 -> grid 628
    const int NB32 = (N_NODES + 31) / 32;   // 625 node-blocks of 32
    // layer 1: z1 = P @ xb (4 slices on XCD pairs) ; h1 = relu(z1 @ W1h + b1) (bf16 out)
    gather_agg_kernel<IN_CH, 4><<<((NB32 + 1) / 2) * 8, 256, 0, stream>>>(
        xb, epair, row_ptr, dinv, z1, N_NODES);
    gemm_mfma_kernel<IN_CH, true, true><<<NMT * 4, 512, 0, stream>>>(z1, wt1_hi, b1, h1,
                                                                     N_NODES, HID_CH);

    // layer 2: z2 = P @ h1 (8 slices, one per XCD) ; out = z2 @ W2h + b2 (fp32 out)
    gather_agg_kernel<HID_CH, 8><<<NB32 * 8, 256, 0, stream>>>(
        h1, epair, row_ptr, dinv, z2, N_NODES);
    gemm_mfma_kernel<HID_CH, false, false><<<NMT * 4, 512, 0, stream>>>(z2, wt2_hi, b2,
                                                                        (float*)d_out, N_NODES,
                                                                        HID_CH);
}